// Round 17
// baseline (317.870 us; speedup 1.0000x reference)
//
#include <hip/hip_runtime.h>
#include <hip/hip_bf16.h>

typedef __attribute__((ext_vector_type(4))) float f32x4;
typedef __attribute__((ext_vector_type(8))) short s16x8;
typedef __attribute__((ext_vector_type(4))) short s16x4;
typedef unsigned short u16;
typedef unsigned long long u64;

#define NB 8
#define NP 12544      // 112*112 output pixels per image
#define PH 114        // padded width/height
#define PP 12996      // 114*114 padded plane
#define PPR 13056     // y row stride (padded plane rounded up, 64-elem aligned)
#define QLIM 12768    // q < QLIM && q%114 < 112  <=> valid output pixel
#define NSEG 196
#define NTOK (NB*NSEG)  // 1568
#define EMB 768
#define HID 512
#define AROWS 368     // A-tile rows staged once: 128 + max tap offset 230 + pad
#define NBUCK 32      // BN1 atomic contention-spreading buckets

__device__ __forceinline__ u16 f2b(float v) {
  __hip_bfloat16 h = __float2bfloat16(v);
  return __builtin_bit_cast(u16, h);
}
__device__ __forceinline__ float b2f(u16 u) {
  unsigned int x = ((unsigned int)u) << 16;
  return __builtin_bit_cast(float, x);
}
__device__ __forceinline__ u16 f2h(float v) {
  _Float16 h = (_Float16)v;
  return __builtin_bit_cast(u16, h);
}
__device__ __forceinline__ float h2f(u16 u) {
  _Float16 h = __builtin_bit_cast(_Float16, u);
  return (float)h;
}
__device__ __forceinline__ u64 pack4h(f32x4 v) {
  s16x4 p;
#pragma unroll
  for (int e = 0; e < 4; ++e) p[e] = (short)f2h(v[e]);
  return __builtin_bit_cast(u64, p);
}

// ---------------- merged weight repacks + lastn (one launch) ----------------
#define PR_WR1 (147 * 64)
#define PR_WR2 (9 * 768 * 64)
#define PR_W1T (512 * 768)
#define PR_W2T (768 * 512)
#define PR_LASTN (NB * NP)
__global__ void k_prep(const float* __restrict__ c1w, const float* __restrict__ c2w,
                       const float* __restrict__ W1, const float* __restrict__ W2,
                       const int* __restrict__ seg,
                       float* __restrict__ wr1, u16* __restrict__ wr2,
                       u16* __restrict__ w1t, u16* __restrict__ w2t,
                       int* __restrict__ lastn) {
  int id = blockIdx.x * 256 + threadIdx.x;
  if (id < PR_WR1) {
    int co = id & 63, k = id >> 6;
    int ci = k / 49, r = k % 49, kh = r / 7, kw = r % 7;
    wr1[k * 64 + co] = c1w[((co * 3 + ci) * 7 + kh) * 7 + kw];
    return;
  }
  id -= PR_WR1;
  if (id < PR_WR2) {
    int ci = id & 63, co = (id >> 6) % 768, tap = id / (64 * 768);
    int kh = tap / 3, kw = tap % 3;
    wr2[((size_t)(tap * 768 + co)) * 64 + ci] = f2b(c2w[((co * 64 + ci) * 3 + kh) * 3 + kw]);
    return;
  }
  id -= PR_WR2;
  if (id < PR_W1T) {
    int k = id % 768, n = id / 768;
    w1t[id] = f2b(W1[(size_t)k * 512 + n]);
    return;
  }
  id -= PR_W1T;
  if (id < PR_W2T) {
    int k = id % 512, n = id / 512;
    w2t[id] = f2b(W2[(size_t)k * 768 + n]);
    return;
  }
  id -= PR_W2T;
  if (id < PR_LASTN) {
    int b = id / NP, n = id % NP;
    int oh = n / 112, ow = n % 112;
    int s = seg[((size_t)b * 224 + oh * 2) * 224 + ow * 2];
    if ((unsigned)s < 196u) atomicMax(&lastn[b * NSEG + s], n);
  }
}

// ---------------- conv1 7x7/s2/p3 -> NHWC bf16 + fused BN1 partial stats ----------------
__global__ __launch_bounds__(256) void k_conv1(const float* __restrict__ img,
                                               const float* __restrict__ wr1,
                                               u16* __restrict__ c1,
                                               float* __restrict__ sumb,
                                               float* __restrict__ sqb) {
  int owt = blockIdx.x, oh = blockIdx.y, b = blockIdx.z;
  int t = threadIdx.x;
  __shared__ float xs[3 * 7 * 37];
  __shared__ float ls[64], lq[64];
  if (t < 64) { ls[t] = 0.f; lq[t] = 0.f; }
  int iw0 = owt * 32 - 3;
  int ih0 = oh * 2 - 3;
  for (int i = t; i < 3 * 7 * 37; i += 256) {
    int ci = i / (7 * 37), r = i % (7 * 37), kh = r / 37, cc = r % 37;
    int ih = ih0 + kh, iw = iw0 + cc;
    float v = 0.f;
    if ((unsigned)ih < 224u && (unsigned)iw < 224u)
      v = img[((size_t)(b * 3 + ci) * 224 + ih) * 224 + iw];
    xs[i] = v;
  }
  __syncthreads();
  int co = t & 63, g = t >> 6;
  float a0 = 0.f, a1 = 0.f, a2 = 0.f, a3 = 0.f;
  for (int ci = 0; ci < 3; ++ci)
    for (int kh = 0; kh < 7; ++kh) {
      const float* xrow = &xs[(ci * 7 + kh) * 37];
      const float* wrow = &wr1[(ci * 49 + kh * 7) * 64 + co];
#pragma unroll
      for (int kw = 0; kw < 7; ++kw) {
        float wv = wrow[kw * 64];
        int base = g * 8 + kw;
        a0 += xrow[base + 0] * wv;
        a1 += xrow[base + 2] * wv;
        a2 += xrow[base + 4] * wv;
        a3 += xrow[base + 6] * wv;
      }
    }
  size_t p0 = (size_t)b * NP + oh * 112 + owt * 16 + g * 4;
  c1[(p0 + 0) * 64 + co] = f2b(a0);
  c1[(p0 + 1) * 64 + co] = f2b(a1);
  c1[(p0 + 2) * 64 + co] = f2b(a2);
  c1[(p0 + 3) * 64 + co] = f2b(a3);
  float s = a0 + a1 + a2 + a3;
  float q = a0 * a0 + a1 * a1 + a2 * a2 + a3 * a3;
  atomicAdd(&ls[co], s);
  atomicAdd(&lq[co], q);
  __syncthreads();
  if (t < 64) {
    int bid = owt + 7 * (oh + 112 * b);
    int bk = (bid & (NBUCK - 1)) * 64 + t;
    atomicAdd(&sumb[bk], ls[t]);
    atomicAdd(&sqb[bk], lq[t]);
  }
}

// ---------------- BN coefficients ----------------
__global__ void k_bncoef(const float* __restrict__ sumb, const float* __restrict__ sqb,
                         const float* __restrict__ g, const float* __restrict__ bb,
                         float* __restrict__ a, float* __restrict__ s, int C, float invN,
                         int nbuck) {
  int i = blockIdx.x * 256 + threadIdx.x;
  if (i >= C) return;
  float ms = 0.f, qs = 0.f;
  for (int k = 0; k < nbuck; ++k) { ms += sumb[k * C + i]; qs += sqb[k * C + i]; }
  float m = ms * invN;
  float v = qs * invN - m * m;
  float ai = g[i] * rsqrtf(v + 1e-5f);
  a[i] = ai;
  s[i] = bb[i] - m * ai;
}

// ---------------- conv2 (3x3, 64->768): A-once (BN1+ReLU fused) + reg-dbuf B, barrier-free loop ----------------
// A staged ONCE from c1 (fused normalize+ReLU, batched loads); B prefetched one
// tap ahead into REGISTERS (no Bs LDS, no barriers in the tap loop). wr2 is
// L2-resident; next-tap loads issue before current tap's 32 MFMAs (latency
// hidden). LDS 47.5KB -> 3 blocks/CU. Coalesced y epilogue (r12-proven).
__global__ __launch_bounds__(256, 3) void k_conv2_stats(const u16* __restrict__ c1,
                                                        const u16* __restrict__ wr2,
                                                        const float* __restrict__ a1,
                                                        const float* __restrict__ s1,
                                                        float* __restrict__ sum,
                                                        float* __restrict__ sq,
                                                        u16* __restrict__ y) {
  const int t = threadIdx.x;
  const int lane = t & 63;
  const int w = t >> 6;
  const int wr = w >> 1, wc = w & 1;
  const int h = blockIdx.x;
  const int b = h & 7;
  const int r8 = h >> 3;            // 0..599
  const int q0 = (r8 / 6) * 128;
  const int co0 = (r8 % 6) * 128;
  const int la = lane & 15, lb = lane >> 4;

  __shared__ __align__(16) u16 As[AROWS * 64];     // 46KB; reused as 32KB y-scratch
  __shared__ float csum[128], csq[128];
  if (t < 128) { csum[t] = 0.f; csq[t] = 0.f; }

  // per-lane B base for this wave's co-half
  const u16* bbase = wr2 + ((size_t)(co0 + wc * 64)) * 64 + lb * 8;
#define LOADB(tap, dst)                                                         \
  _Pragma("unroll")                                                             \
  for (int cf_ = 0; cf_ < 4; ++cf_)                                             \
    _Pragma("unroll")                                                           \
    for (int ks_ = 0; ks_ < 2; ++ks_)                                           \
      dst[cf_][ks_] = *(const s16x8*)(bbase + ((size_t)(tap) * 768 + cf_ * 16 + la) * 64 + ks_ * 32);

  s16x8 bf[4][2], bn[4][2];
  LOADB(0, bf);

  // stage A once from c1 with fused BN1+ReLU; loads batched ahead of converts
  {
    const u16* c1b = c1 + (size_t)b * NP * 64;
    const int c = t & 7;   // fixed channel-octet per thread
    f32x4 aLo = *(const f32x4*)&a1[c * 8];
    f32x4 aHi = *(const f32x4*)&a1[c * 8 + 4];
    f32x4 sLo = *(const f32x4*)&s1[c * 8];
    f32x4 sHi = *(const f32x4*)&s1[c * 8 + 4];
#pragma unroll
    for (int hh = 0; hh < 2; ++hh) {
      s16x8 vv[6];
      bool ok0, ok1, ok2, ok3, ok4, ok5;
#pragma unroll
      for (int i = 0; i < 6; ++i) {
        int s = (hh * 6 + i) * 256 + t;
        int r = s >> 3;
        int p = q0 + r;
        int pd = p / PH, pm = p - pd * PH;
        bool valid = (s < AROWS * 8) && (pd >= 1) && (pd <= 112) && (pm >= 1) && (pm <= 112);
        int pix = valid ? ((pd - 1) * 112 + (pm - 1)) : 0;
        vv[i] = *(const s16x8*)&c1b[(size_t)pix * 64 + c * 8];
        if (i == 0) ok0 = valid; else if (i == 1) ok1 = valid; else if (i == 2) ok2 = valid;
        else if (i == 3) ok3 = valid; else if (i == 4) ok4 = valid; else ok5 = valid;
      }
#pragma unroll
      for (int i = 0; i < 6; ++i) {
        int s = (hh * 6 + i) * 256 + t;
        if (s < AROWS * 8) {
          int r = s >> 3;
          bool valid = (i == 0) ? ok0 : (i == 1) ? ok1 : (i == 2) ? ok2
                     : (i == 3) ? ok3 : (i == 4) ? ok4 : ok5;
          s16x8 o = {0, 0, 0, 0, 0, 0, 0, 0};
          if (valid) {
            s16x8 v = vv[i];
#pragma unroll
            for (int e = 0; e < 4; ++e) {
              o[e]     = (short)f2b(fmaxf(aLo[e] * b2f((u16)v[e])     + sLo[e], 0.f));
              o[e + 4] = (short)f2b(fmaxf(aHi[e] * b2f((u16)v[e + 4]) + sHi[e], 0.f));
            }
          }
          *(s16x8*)&As[r * 64 + ((c ^ (r & 7)) * 8)] = o;
        }
      }
    }
  }
  __syncthreads();   // A tile visible to all waves (the ONLY pre-loop barrier)

  const f32x4 zero4 = {0.f, 0.f, 0.f, 0.f};
  f32x4 acc[4][4];
#pragma unroll
  for (int i = 0; i < 4; ++i)
#pragma unroll
    for (int j = 0; j < 4; ++j) acc[i][j] = zero4;

#pragma unroll
  for (int tap = 0; tap < 9; ++tap) {
    if (tap < 8) LOADB(tap + 1, bn);   // next-tap B in flight under this tap's MFMAs
    const int off = (tap / 3) * PH + (tap % 3);

#pragma unroll
    for (int ks = 0; ks < 2; ++ks) {
      s16x8 af[4];
#pragma unroll
      for (int qf = 0; qf < 4; ++qf) {
        int r = wr * 64 + qf * 16 + la + off;
        int slot = (ks * 4 + lb) ^ (r & 7);
        af[qf] = *(const s16x8*)&As[r * 64 + slot * 8];
      }
#pragma unroll
      for (int qf = 0; qf < 4; ++qf)
#pragma unroll
        for (int cf = 0; cf < 4; ++cf)
          acc[qf][cf] = __builtin_amdgcn_mfma_f32_16x16x32_bf16(af[qf], bf[cf][ks], acc[qf][cf], 0, 0, 0);
    }

    if (tap < 8) {
#pragma unroll
      for (int cf = 0; cf < 4; ++cf)
#pragma unroll
        for (int ks = 0; ks < 2; ++ks)
          bf[cf][ks] = bn[cf][ks];
    }
  }
#undef LOADB

  __syncthreads();   // all waves done reading As -> safe to reuse as scratch

  // ---- epilogue part 1: pack acc -> LDS scratch (reuse As), XOR swizzle ----
  u64* S = (u64*)As;   // [128 rows][32 chunks of 8B] = 32KB
#pragma unroll
  for (int cf = 0; cf < 4; ++cf) {
    int row = wc * 64 + cf * 16 + la;
#pragma unroll
    for (int qf = 0; qf < 4; ++qf) {
      int chunk = wr * 16 + qf * 4 + lb;
      S[row * 32 + (chunk ^ (row & 15))] = pack4h(acc[qf][cf]);
    }
  }

  // ---- stats (masked, from registers) ----
  bool vmask[16];
#pragma unroll
  for (int qf = 0; qf < 4; ++qf)
#pragma unroll
    for (int rr = 0; rr < 4; ++rr) {
      int q = q0 + wr * 64 + qf * 16 + lb * 4 + rr;
      vmask[qf * 4 + rr] = (q < QLIM) && ((q % PH) < 112);
    }
#pragma unroll
  for (int cf = 0; cf < 4; ++cf) {
    const int cob = wc * 64 + cf * 16 + la;
    float s = 0.f, ss = 0.f;
#pragma unroll
    for (int qf = 0; qf < 4; ++qf)
#pragma unroll
      for (int rr = 0; rr < 4; ++rr) {
        float v = acc[qf][cf][rr];
        if (vmask[qf * 4 + rr]) { s += v; ss += v * v; }
      }
    s += __shfl_xor(s, 16); ss += __shfl_xor(ss, 16);
    s += __shfl_xor(s, 32); ss += __shfl_xor(ss, 32);
    if (lane < 16) { atomicAdd(&csum[cob], s); atomicAdd(&csq[cob], ss); }
  }
  __syncthreads();   // S writes + csum atomics visible

  // ---- epilogue part 2: coalesced store (wave = 2 rows x 256B) ----
  {
    const size_t ybb = ((size_t)b * EMB + co0) * PPR + q0;
#pragma unroll
    for (int i = 0; i < 16; ++i) {
      int g = i * 256 + t;
      int row = g >> 5, c = g & 31;
      u64 pk = S[row * 32 + (c ^ (row & 15))];
      *(u64*)&y[ybb + (size_t)row * PPR + c * 4] = pk;
    }
  }
  if (t < 128) { atomicAdd(&sum[co0 + t], csum[t]); atomicAdd(&sq[co0 + t], csq[t]); }
}

// ---------------- token assembly: slice of padded y + BN2 + ReLU + pos -> x bf16 ----------------
__global__ __launch_bounds__(256) void k_token_out(const u16* __restrict__ y,
                                                   const int* __restrict__ lastn,
                                                   const float* __restrict__ a2,
                                                   const float* __restrict__ s2,
                                                   const float* __restrict__ pos,
                                                   u16* __restrict__ x) {
  int tok = blockIdx.x;
  int b = tok / NSEG, sg = tok % NSEG;
  int n = lastn[tok];
  int t = threadIdx.x;
  for (int c = t; c < EMB; c += 256) {
    float r = 0.f;
    if (n >= 0) {
      int j = n * EMB + c;         // flat index in unpadded [768][12544] view
      int ch = j / NP, sp = j - ch * NP;
      int qd = sp / 112, qm = sp - qd * 112;
      float v = h2f(y[((size_t)b * EMB + ch) * PPR + qd * PH + qm]);
      r = fmaxf(a2[ch] * v + s2[ch], 0.f) + pos[(size_t)sg * EMB + c];
    }
    x[(size_t)tok * EMB + c] = f2b(r);
  }
}

// ---------------- MLP layer 1: h = gelu(x @ W1 + b1) ----------------
__global__ __launch_bounds__(256) void k_mlp1(const u16* __restrict__ x,
                                              const u16* __restrict__ w1t,
                                              const float* __restrict__ b1,
                                              u16* __restrict__ h) {
  int t = threadIdx.x, lane = t & 63, w = t >> 6;
  int la = lane & 15, lb = lane >> 4;
  int m0 = (blockIdx.x * 4 + w) * 16;
  int n0 = blockIdx.y * 64;
  const f32x4 zero4 = {0.f, 0.f, 0.f, 0.f};
  f32x4 acc[4] = {zero4, zero4, zero4, zero4};
  int mrow = m0 + la; if (mrow >= NTOK) mrow = NTOK - 1;
  for (int k = 0; k < EMB; k += 32) {
    int ko = k + lb * 8;
    s16x8 a = *(const s16x8*)(x + (size_t)mrow * EMB + ko);
#pragma unroll
    for (int cf = 0; cf < 4; ++cf) {
      s16x8 bv = *(const s16x8*)(w1t + (size_t)(n0 + cf * 16 + la) * EMB + ko);
      acc[cf] = __builtin_amdgcn_mfma_f32_16x16x32_bf16(a, bv, acc[cf], 0, 0, 0);
    }
  }
#pragma unroll
  for (int cf = 0; cf < 4; ++cf) {
    int n = n0 + cf * 16 + la;
    float bias = b1[n];
#pragma unroll
    for (int r = 0; r < 4; ++r) {
      int m = m0 + lb * 4 + r;
      if (m < NTOK) {
        float v = acc[cf][r] + bias;
        float gg = 0.5f * v * (1.f + erff(v * 0.70710678118654752f));
        h[(size_t)m * HID + n] = f2b(gg);
      }
    }
  }
}

// ---------------- MLP layer 2: y = h @ W2 + b2 -> d_out (zeros for absent tokens) ----------------
__global__ __launch_bounds__(256) void k_mlp2(const u16* __restrict__ h,
                                              const u16* __restrict__ w2t,
                                              const float* __restrict__ b2,
                                              const int* __restrict__ lastn,
                                              float* __restrict__ out) {
  int t = threadIdx.x, lane = t & 63, w = t >> 6;
  int la = lane & 15, lb = lane >> 4;
  int m0 = (blockIdx.x * 4 + w) * 16;
  int n0 = blockIdx.y * 64;
  const f32x4 zero4 = {0.f, 0.f, 0.f, 0.f};
  f32x4 acc[4] = {zero4, zero4, zero4, zero4};
  int mrow = m0 + la; if (mrow >= NTOK) mrow = NTOK - 1;
  for (int k = 0; k < HID; k += 32) {
    int ko = k + lb * 8;
    s16x8 a = *(const s16x8*)(h + (size_t)mrow * HID + ko);
#pragma unroll
    for (int cf = 0; cf < 4; ++cf) {
      s16x8 bv = *(const s16x8*)(w2t + (size_t)(n0 + cf * 16 + la) * HID + ko);
      acc[cf] = __builtin_amdgcn_mfma_f32_16x16x32_bf16(a, bv, acc[cf], 0, 0, 0);
    }
  }
#pragma unroll
  for (int cf = 0; cf < 4; ++cf) {
    int n = n0 + cf * 16 + la;
    float bias = b2[n];
#pragma unroll
    for (int r = 0; r < 4; ++r) {
      int m = m0 + lb * 4 + r;
      if (m < NTOK)
        out[(size_t)m * EMB + n] = (lastn[m] >= 0) ? (acc[cf][r] + bias) : 0.f;
    }
  }
}

extern "C" void kernel_launch(void* const* d_in, const int* in_sizes, int n_in,
                              void* d_out, int out_size, void* d_ws, size_t ws_size,
                              hipStream_t stream) {
  const float* img  = (const float*)d_in[0];
  const int*   seg  = (const int*)  d_in[1];
  const float* c1w  = (const float*)d_in[2];
  const float* bn1g = (const float*)d_in[4];
  const float* bn1b = (const float*)d_in[5];
  const float* c2w  = (const float*)d_in[6];
  const float* bn2g = (const float*)d_in[8];
  const float* bn2b = (const float*)d_in[9];
  const float* pos  = (const float*)d_in[10];
  const float* W1   = (const float*)d_in[11];
  const float* b1   = (const float*)d_in[12];
  const float* W2   = (const float*)d_in[13];
  const float* b2   = (const float*)d_in[14];

  char* ws = (char*)d_ws;
  size_t off = 0;
  auto alloc = [&](size_t bytes) { size_t o = off; off = (off + bytes + 255) & ~(size_t)255; return o; };

  size_t oC1  = alloc((size_t)NB * NP * 64 * 2);    // conv1 out, bf16 NHWC
  size_t oY   = alloc((size_t)NB * EMB * PPR * 2);  // raw conv2 output, fp16, PADDED rows
  size_t oWr2 = alloc((size_t)9 * 768 * 64 * 2);
  size_t oWr1 = alloc(147 * 64 * 4);
  size_t oW1T = alloc((size_t)HID * EMB * 2);
  size_t oW2T = alloc((size_t)EMB * HID * 2);
  size_t oSum = alloc((NBUCK * 64 * 2 + 768 + 768) * 4);
  size_t oCoef = alloc((64 + 64 + 768 + 768) * 4);
  size_t oLast = alloc(NTOK * 4);
  size_t oX   = alloc((size_t)NTOK * EMB * 2);
  size_t oH   = alloc((size_t)NTOK * HID * 2);
  (void)ws_size; (void)in_sizes; (void)n_in;

  u16*   c1   = (u16*)(ws + oC1);
  u16*   y    = (u16*)(ws + oY);
  u16*   wr2  = (u16*)(ws + oWr2);
  float* wr1  = (float*)(ws + oWr1);
  u16*   w1t  = (u16*)(ws + oW1T);
  u16*   w2t  = (u16*)(ws + oW2T);
  float* bn1sumb = (float*)(ws + oSum);           // [NBUCK][64]
  float* bn1sqb  = bn1sumb + NBUCK * 64;          // [NBUCK][64]
  float* bn2sum  = bn1sumb + NBUCK * 64 * 2;      // [768]
  float* bn2sq   = bn2sum + 768;                  // [768]
  float* a1 = (float*)(ws + oCoef);
  float* s1 = a1 + 64;
  float* a2 = a1 + 128;
  float* s2 = a2 + 768;
  int*   lastn = (int*)(ws + oLast);
  u16*   x  = (u16*)(ws + oX);
  u16*   h  = (u16*)(ws + oH);
  float* out = (float*)d_out;

  hipMemsetAsync(ws + oSum, 0, (NBUCK * 64 * 2 + 768 + 768) * 4, stream);
  hipMemsetAsync(ws + oLast, 0xFF, NTOK * 4, stream);

  const int prep_total = PR_WR1 + PR_WR2 + PR_W1T + PR_W2T + PR_LASTN;
  k_prep<<<(prep_total + 255) / 256, 256, 0, stream>>>(c1w, c2w, W1, W2, seg,
                                                        wr1, wr2, w1t, w2t, lastn);

  k_conv1<<<dim3(7, 112, 8), 256, 0, stream>>>(img, wr1, c1, bn1sumb, bn1sqb);
  k_bncoef<<<1, 256, 0, stream>>>(bn1sumb, bn1sqb, bn1g, bn1b, a1, s1, 64, 1.f / 100352.f, NBUCK);

  k_conv2_stats<<<4800, 256, 0, stream>>>(c1, wr2, a1, s1, bn2sum, bn2sq, y);
  k_bncoef<<<3, 256, 0, stream>>>(bn2sum, bn2sq, bn2g, bn2b, a2, s2, 768, 1.f / 100352.f, 1);

  k_token_out<<<NTOK, 256, 0, stream>>>(y, lastn, a2, s2, pos, x);

  k_mlp1<<<dim3(25, 8), 256, 0, stream>>>(x, w1t, b1, h);
  k_mlp2<<<dim3(25, 12), 256, 0, stream>>>(h, w2t, b2, lastn, out);
}

// Round 18
// 265.246 us; speedup vs baseline: 1.1984x; 1.1984x over previous
//
#include <hip/hip_runtime.h>
#include <hip/hip_bf16.h>

typedef __attribute__((ext_vector_type(4))) float f32x4;
typedef __attribute__((ext_vector_type(8))) short s16x8;
typedef __attribute__((ext_vector_type(4))) short s16x4;
typedef unsigned short u16;
typedef unsigned long long u64;

#define NB 8
#define NP 12544      // 112*112 output pixels per image
#define PH 114        // padded width/height
#define PP 12996      // 114*114 padded plane
#define PPR 13056     // y row stride (padded plane rounded up, 64-elem aligned)
#define QLIM 12768    // q < QLIM && q%114 < 112  <=> valid output pixel
#define NSEG 196
#define NTOK (NB*NSEG)  // 1568
#define EMB 768
#define HID 512
#define AROWS 368     // A-tile rows staged once: 128 + max tap offset 230 + pad
#define NBUCK 32      // BN1 atomic contention-spreading buckets

__device__ __forceinline__ u16 f2b(float v) {
  __hip_bfloat16 h = __float2bfloat16(v);
  return __builtin_bit_cast(u16, h);
}
__device__ __forceinline__ float b2f(u16 u) {
  unsigned int x = ((unsigned int)u) << 16;
  return __builtin_bit_cast(float, x);
}
__device__ __forceinline__ u16 f2h(float v) {
  _Float16 h = (_Float16)v;
  return __builtin_bit_cast(u16, h);
}
__device__ __forceinline__ float h2f(u16 u) {
  _Float16 h = __builtin_bit_cast(_Float16, u);
  return (float)h;
}
__device__ __forceinline__ u64 pack4h(f32x4 v) {
  s16x4 p;
#pragma unroll
  for (int e = 0; e < 4; ++e) p[e] = (short)f2h(v[e]);
  return __builtin_bit_cast(u64, p);
}

// async global->LDS, 16B per lane; lds dest = wave-uniform base + lane*16
__device__ __forceinline__ void gl16(const u16* g, u16* l) {
  __builtin_amdgcn_global_load_lds((const __attribute__((address_space(1))) void*)g,
                                   (__attribute__((address_space(3))) void*)l, 16, 0, 0);
}

// ---------------- merged weight repacks + lastn (one launch) ----------------
#define PR_WR1 (147 * 64)
#define PR_WR2 (9 * 768 * 64)
#define PR_W1T (512 * 768)
#define PR_W2T (768 * 512)
#define PR_LASTN (NB * NP)
__global__ void k_prep(const float* __restrict__ c1w, const float* __restrict__ c2w,
                       const float* __restrict__ W1, const float* __restrict__ W2,
                       const int* __restrict__ seg,
                       float* __restrict__ wr1, u16* __restrict__ wr2,
                       u16* __restrict__ w1t, u16* __restrict__ w2t,
                       int* __restrict__ lastn) {
  int id = blockIdx.x * 256 + threadIdx.x;
  if (id < PR_WR1) {
    int co = id & 63, k = id >> 6;
    int ci = k / 49, r = k % 49, kh = r / 7, kw = r % 7;
    wr1[k * 64 + co] = c1w[((co * 3 + ci) * 7 + kh) * 7 + kw];
    return;
  }
  id -= PR_WR1;
  if (id < PR_WR2) {
    int ci = id & 63, co = (id >> 6) % 768, tap = id / (64 * 768);
    int kh = tap / 3, kw = tap % 3;
    wr2[((size_t)(tap * 768 + co)) * 64 + ci] = f2b(c2w[((co * 64 + ci) * 3 + kh) * 3 + kw]);
    return;
  }
  id -= PR_WR2;
  if (id < PR_W1T) {
    int k = id % 768, n = id / 768;
    w1t[id] = f2b(W1[(size_t)k * 512 + n]);
    return;
  }
  id -= PR_W1T;
  if (id < PR_W2T) {
    int k = id % 512, n = id / 512;
    w2t[id] = f2b(W2[(size_t)k * 768 + n]);
    return;
  }
  id -= PR_W2T;
  if (id < PR_LASTN) {
    int b = id / NP, n = id % NP;
    int oh = n / 112, ow = n % 112;
    int s = seg[((size_t)b * 224 + oh * 2) * 224 + ow * 2];
    if ((unsigned)s < 196u) atomicMax(&lastn[b * NSEG + s], n);
  }
}

// ---------------- conv1 7x7/s2/p3 -> NHWC bf16 + fused BN1 partial stats ----------------
__global__ __launch_bounds__(256) void k_conv1(const float* __restrict__ img,
                                               const float* __restrict__ wr1,
                                               u16* __restrict__ c1,
                                               float* __restrict__ sumb,
                                               float* __restrict__ sqb) {
  int owt = blockIdx.x, oh = blockIdx.y, b = blockIdx.z;
  int t = threadIdx.x;
  __shared__ float xs[3 * 7 * 37];
  __shared__ float ls[64], lq[64];
  if (t < 64) { ls[t] = 0.f; lq[t] = 0.f; }
  int iw0 = owt * 32 - 3;
  int ih0 = oh * 2 - 3;
  for (int i = t; i < 3 * 7 * 37; i += 256) {
    int ci = i / (7 * 37), r = i % (7 * 37), kh = r / 37, cc = r % 37;
    int ih = ih0 + kh, iw = iw0 + cc;
    float v = 0.f;
    if ((unsigned)ih < 224u && (unsigned)iw < 224u)
      v = img[((size_t)(b * 3 + ci) * 224 + ih) * 224 + iw];
    xs[i] = v;
  }
  __syncthreads();
  int co = t & 63, g = t >> 6;
  float a0 = 0.f, a1 = 0.f, a2 = 0.f, a3 = 0.f;
  for (int ci = 0; ci < 3; ++ci)
    for (int kh = 0; kh < 7; ++kh) {
      const float* xrow = &xs[(ci * 7 + kh) * 37];
      const float* wrow = &wr1[(ci * 49 + kh * 7) * 64 + co];
#pragma unroll
      for (int kw = 0; kw < 7; ++kw) {
        float wv = wrow[kw * 64];
        int base = g * 8 + kw;
        a0 += xrow[base + 0] * wv;
        a1 += xrow[base + 2] * wv;
        a2 += xrow[base + 4] * wv;
        a3 += xrow[base + 6] * wv;
      }
    }
  size_t p0 = (size_t)b * NP + oh * 112 + owt * 16 + g * 4;
  c1[(p0 + 0) * 64 + co] = f2b(a0);
  c1[(p0 + 1) * 64 + co] = f2b(a1);
  c1[(p0 + 2) * 64 + co] = f2b(a2);
  c1[(p0 + 3) * 64 + co] = f2b(a3);
  float s = a0 + a1 + a2 + a3;
  float q = a0 * a0 + a1 * a1 + a2 * a2 + a3 * a3;
  atomicAdd(&ls[co], s);
  atomicAdd(&lq[co], q);
  __syncthreads();
  if (t < 64) {
    int bid = owt + 7 * (oh + 112 * b);
    int bk = (bid & (NBUCK - 1)) * 64 + t;
    atomicAdd(&sumb[bk], ls[t]);
    atomicAdd(&sqb[bk], lq[t]);
  }
}

// ---------------- BN coefficients ----------------
__global__ void k_bncoef(const float* __restrict__ sumb, const float* __restrict__ sqb,
                         const float* __restrict__ g, const float* __restrict__ bb,
                         float* __restrict__ a, float* __restrict__ s, int C, float invN,
                         int nbuck) {
  int i = blockIdx.x * 256 + threadIdx.x;
  if (i >= C) return;
  float ms = 0.f, qs = 0.f;
  for (int k = 0; k < nbuck; ++k) { ms += sumb[k * C + i]; qs += sqb[k * C + i]; }
  float m = ms * invN;
  float v = qs * invN - m * m;
  float ai = g[i] * rsqrtf(v + 1e-5f);
  a[i] = ai;
  s[i] = bb[i] - m * ai;
}

// ---------------- conv2 (3x3, 64->768): A-once serves 3 co-tiles; B LDS-dbuf; coalesced epilogue ----------------
// grid 1600: b = h&7, r = h>>3 (0..199): q0 = (r>>1)*128, ccg = r&1 -> co-tiles ccg*3+{0,1,2}.
// A staged ONCE (fused BN1+ReLU, batched loads) and reused across 3 co-tiles
// (amortizes the r16 staging cost 3x). Inner tap loop = r16-proven (Bs dbuf via
// global_load_lds, one barrier/tap). Epilogue scratch = dead Bs.
__global__ __launch_bounds__(256, 2) void k_conv2_stats(const u16* __restrict__ c1,
                                                        const u16* __restrict__ wr2,
                                                        const float* __restrict__ a1,
                                                        const float* __restrict__ s1,
                                                        float* __restrict__ sum,
                                                        float* __restrict__ sq,
                                                        u16* __restrict__ y) {
  const int t = threadIdx.x;
  const int lane = t & 63;
  const int w = t >> 6;
  const int wr = w >> 1, wc = w & 1;
  const int h = blockIdx.x;
  const int b = h & 7;
  const int r8 = h >> 3;            // 0..199
  const int q0 = (r8 >> 1) * 128;
  const int ccg = r8 & 1;
  const int la = lane & 15, lb = lane >> 4;

  __shared__ __align__(16) u16 As[AROWS * 64];     // 46KB, live across all co-tiles
  __shared__ __align__(16) u16 Bs[2][8192];        // 2 x 16KB; reused as epilogue scratch
  __shared__ float csum[128], csq[128];

#define BSTAGE(tap, buf, co0_) do {                                             \
    const u16* bsrc_ = wr2 + ((size_t)((tap) * 768 + (co0_))) * 64;              \
    _Pragma("unroll")                                                            \
    for (int i_ = 0; i_ < 4; ++i_) {                                             \
      int s_ = i_ * 256 + w * 64 + lane;                                         \
      int r_ = s_ >> 3, c_ = s_ & 7;                                             \
      int cg_ = c_ ^ (r_ & 7);                                                   \
      gl16(bsrc_ + (size_t)r_ * 64 + cg_ * 8,                                    \
           &Bs[buf][(size_t)(i_ * 256 + w * 64) * 8]);                           \
    }                                                                            \
  } while (0)

  // stage A once from c1 with fused BN1+ReLU; loads batched ahead of converts
  {
    const u16* c1b = c1 + (size_t)b * NP * 64;
    const int c = t & 7;   // fixed channel-octet per thread
    f32x4 aLo = *(const f32x4*)&a1[c * 8];
    f32x4 aHi = *(const f32x4*)&a1[c * 8 + 4];
    f32x4 sLo = *(const f32x4*)&s1[c * 8];
    f32x4 sHi = *(const f32x4*)&s1[c * 8 + 4];
#pragma unroll
    for (int hh = 0; hh < 2; ++hh) {
      s16x8 vv[6];
      bool ok0, ok1, ok2, ok3, ok4, ok5;
#pragma unroll
      for (int i = 0; i < 6; ++i) {
        int s = (hh * 6 + i) * 256 + t;
        int r = s >> 3;
        int p = q0 + r;
        int pd = p / PH, pm = p - pd * PH;
        bool valid = (s < AROWS * 8) && (pd >= 1) && (pd <= 112) && (pm >= 1) && (pm <= 112);
        int pix = valid ? ((pd - 1) * 112 + (pm - 1)) : 0;
        vv[i] = *(const s16x8*)&c1b[(size_t)pix * 64 + c * 8];
        if (i == 0) ok0 = valid; else if (i == 1) ok1 = valid; else if (i == 2) ok2 = valid;
        else if (i == 3) ok3 = valid; else if (i == 4) ok4 = valid; else ok5 = valid;
      }
#pragma unroll
      for (int i = 0; i < 6; ++i) {
        int s = (hh * 6 + i) * 256 + t;
        if (s < AROWS * 8) {
          int r = s >> 3;
          bool valid = (i == 0) ? ok0 : (i == 1) ? ok1 : (i == 2) ? ok2
                     : (i == 3) ? ok3 : (i == 4) ? ok4 : ok5;
          s16x8 o = {0, 0, 0, 0, 0, 0, 0, 0};
          if (valid) {
            s16x8 v = vv[i];
#pragma unroll
            for (int e = 0; e < 4; ++e) {
              o[e]     = (short)f2b(fmaxf(aLo[e] * b2f((u16)v[e])     + sLo[e], 0.f));
              o[e + 4] = (short)f2b(fmaxf(aHi[e] * b2f((u16)v[e + 4]) + sHi[e], 0.f));
            }
          }
          *(s16x8*)&As[r * 64 + ((c ^ (r & 7)) * 8)] = o;
        }
      }
    }
  }

  // hoisted per-lane q metadata (same for all co-tiles)
  bool vmask[16];
#pragma unroll
  for (int qf = 0; qf < 4; ++qf)
#pragma unroll
    for (int rr = 0; rr < 4; ++rr) {
      int q = q0 + wr * 64 + qf * 16 + lb * 4 + rr;
      vmask[qf * 4 + rr] = (q < QLIM) && ((q % PH) < 112);
    }

  const f32x4 zero4 = {0.f, 0.f, 0.f, 0.f};

  for (int j = 0; j < 3; ++j) {
    const int co0 = (ccg * 3 + j) * 128;
    if (t < 128) { csum[t] = 0.f; csq[t] = 0.f; }
    BSTAGE(0, 0, co0);
    __syncthreads();   // A visible (j=0) / Bs free (j>0); B0 landed; csum init visible

    f32x4 acc[4][4];
#pragma unroll
    for (int i = 0; i < 4; ++i)
#pragma unroll
      for (int jj = 0; jj < 4; ++jj) acc[i][jj] = zero4;

    for (int tap = 0; tap < 9; ++tap) {
      const int off = (tap / 3) * PH + (tap % 3);
      const int buf = tap & 1;

      s16x8 af[4][2], bf[4][2];
#pragma unroll
      for (int qf = 0; qf < 4; ++qf) {
        int r = wr * 64 + qf * 16 + la + off;
        int rx = r & 7;
#pragma unroll
        for (int ks = 0; ks < 2; ++ks) {
          int slot = (ks * 4 + lb) ^ rx;
          af[qf][ks] = *(const s16x8*)&As[r * 64 + slot * 8];
        }
      }
#pragma unroll
      for (int cf = 0; cf < 4; ++cf) {
        int r = wc * 64 + cf * 16 + la;
        int rx = r & 7;
#pragma unroll
        for (int ks = 0; ks < 2; ++ks) {
          int slot = (ks * 4 + lb) ^ rx;
          bf[cf][ks] = *(const s16x8*)&Bs[buf][r * 64 + slot * 8];
        }
      }

      if (tap < 8) BSTAGE(tap + 1, buf ^ 1, co0);   // flies under the MFMAs

#pragma unroll
      for (int ks = 0; ks < 2; ++ks)
#pragma unroll
        for (int qf = 0; qf < 4; ++qf)
#pragma unroll
          for (int cf = 0; cf < 4; ++cf)
            acc[qf][cf] = __builtin_amdgcn_mfma_f32_16x16x32_bf16(af[qf][ks], bf[cf][ks], acc[qf][cf], 0, 0, 0);

      __syncthreads();   // one barrier per tap
    }

    // ---- epilogue part 1: pack acc -> LDS scratch (Bs is dead), XOR swizzle ----
    u64* S = (u64*)Bs;   // [128 rows][32 chunks of 8B] = 32KB
#pragma unroll
    for (int cf = 0; cf < 4; ++cf) {
      int row = wc * 64 + cf * 16 + la;
#pragma unroll
      for (int qf = 0; qf < 4; ++qf) {
        int chunk = wr * 16 + qf * 4 + lb;
        S[row * 32 + (chunk ^ (row & 15))] = pack4h(acc[qf][cf]);
      }
    }

    // ---- stats (masked, from registers) ----
#pragma unroll
    for (int cf = 0; cf < 4; ++cf) {
      const int cob = wc * 64 + cf * 16 + la;
      float s = 0.f, ss = 0.f;
#pragma unroll
      for (int qf = 0; qf < 4; ++qf)
#pragma unroll
        for (int rr = 0; rr < 4; ++rr) {
          float v = acc[qf][cf][rr];
          if (vmask[qf * 4 + rr]) { s += v; ss += v * v; }
        }
      s += __shfl_xor(s, 16); ss += __shfl_xor(ss, 16);
      s += __shfl_xor(s, 32); ss += __shfl_xor(ss, 32);
      if (lane < 16) { atomicAdd(&csum[cob], s); atomicAdd(&csq[cob], ss); }
    }
    __syncthreads();   // S writes + csum atomics visible

    // ---- epilogue part 2: coalesced store (wave = 2 rows x 256B) ----
    {
      const size_t ybb = ((size_t)b * EMB + co0) * PPR + q0;
#pragma unroll
      for (int i = 0; i < 16; ++i) {
        int g = i * 256 + t;
        int row = g >> 5, c = g & 31;
        u64 pk = S[row * 32 + (c ^ (row & 15))];
        *(u64*)&y[ybb + (size_t)row * PPR + c * 4] = pk;
      }
    }
    if (t < 128) { atomicAdd(&sum[co0 + t], csum[t]); atomicAdd(&sq[co0 + t], csq[t]); }
    __syncthreads();   // stores done reading S before next j overwrites Bs
  }
#undef BSTAGE
}

// ---------------- token assembly: slice of padded y + BN2 + ReLU + pos -> x bf16 ----------------
__global__ __launch_bounds__(256) void k_token_out(const u16* __restrict__ y,
                                                   const int* __restrict__ lastn,
                                                   const float* __restrict__ a2,
                                                   const float* __restrict__ s2,
                                                   const float* __restrict__ pos,
                                                   u16* __restrict__ x) {
  int tok = blockIdx.x;
  int b = tok / NSEG, sg = tok % NSEG;
  int n = lastn[tok];
  int t = threadIdx.x;
  for (int c = t; c < EMB; c += 256) {
    float r = 0.f;
    if (n >= 0) {
      int j = n * EMB + c;         // flat index in unpadded [768][12544] view
      int ch = j / NP, sp = j - ch * NP;
      int qd = sp / 112, qm = sp - qd * 112;
      float v = h2f(y[((size_t)b * EMB + ch) * PPR + qd * PH + qm]);
      r = fmaxf(a2[ch] * v + s2[ch], 0.f) + pos[(size_t)sg * EMB + c];
    }
    x[(size_t)tok * EMB + c] = f2b(r);
  }
}

// ---------------- MLP layer 1: h = gelu(x @ W1 + b1) ----------------
__global__ __launch_bounds__(256) void k_mlp1(const u16* __restrict__ x,
                                              const u16* __restrict__ w1t,
                                              const float* __restrict__ b1,
                                              u16* __restrict__ h) {
  int t = threadIdx.x, lane = t & 63, w = t >> 6;
  int la = lane & 15, lb = lane >> 4;
  int m0 = (blockIdx.x * 4 + w) * 16;
  int n0 = blockIdx.y * 64;
  const f32x4 zero4 = {0.f, 0.f, 0.f, 0.f};
  f32x4 acc[4] = {zero4, zero4, zero4, zero4};
  int mrow = m0 + la; if (mrow >= NTOK) mrow = NTOK - 1;
  for (int k = 0; k < EMB; k += 32) {
    int ko = k + lb * 8;
    s16x8 a = *(const s16x8*)(x + (size_t)mrow * EMB + ko);
#pragma unroll
    for (int cf = 0; cf < 4; ++cf) {
      s16x8 bv = *(const s16x8*)(w1t + (size_t)(n0 + cf * 16 + la) * EMB + ko);
      acc[cf] = __builtin_amdgcn_mfma_f32_16x16x32_bf16(a, bv, acc[cf], 0, 0, 0);
    }
  }
#pragma unroll
  for (int cf = 0; cf < 4; ++cf) {
    int n = n0 + cf * 16 + la;
    float bias = b1[n];
#pragma unroll
    for (int r = 0; r < 4; ++r) {
      int m = m0 + lb * 4 + r;
      if (m < NTOK) {
        float v = acc[cf][r] + bias;
        float gg = 0.5f * v * (1.f + erff(v * 0.70710678118654752f));
        h[(size_t)m * HID + n] = f2b(gg);
      }
    }
  }
}

// ---------------- MLP layer 2: y = h @ W2 + b2 -> d_out (zeros for absent tokens) ----------------
__global__ __launch_bounds__(256) void k_mlp2(const u16* __restrict__ h,
                                              const u16* __restrict__ w2t,
                                              const float* __restrict__ b2,
                                              const int* __restrict__ lastn,
                                              float* __restrict__ out) {
  int t = threadIdx.x, lane = t & 63, w = t >> 6;
  int la = lane & 15, lb = lane >> 4;
  int m0 = (blockIdx.x * 4 + w) * 16;
  int n0 = blockIdx.y * 64;
  const f32x4 zero4 = {0.f, 0.f, 0.f, 0.f};
  f32x4 acc[4] = {zero4, zero4, zero4, zero4};
  int mrow = m0 + la; if (mrow >= NTOK) mrow = NTOK - 1;
  for (int k = 0; k < HID; k += 32) {
    int ko = k + lb * 8;
    s16x8 a = *(const s16x8*)(h + (size_t)mrow * HID + ko);
#pragma unroll
    for (int cf = 0; cf < 4; ++cf) {
      s16x8 bv = *(const s16x8*)(w2t + (size_t)(n0 + cf * 16 + la) * HID + ko);
      acc[cf] = __builtin_amdgcn_mfma_f32_16x16x32_bf16(a, bv, acc[cf], 0, 0, 0);
    }
  }
#pragma unroll
  for (int cf = 0; cf < 4; ++cf) {
    int n = n0 + cf * 16 + la;
    float bias = b2[n];
#pragma unroll
    for (int r = 0; r < 4; ++r) {
      int m = m0 + lb * 4 + r;
      if (m < NTOK)
        out[(size_t)m * EMB + n] = (lastn[m] >= 0) ? (acc[cf][r] + bias) : 0.f;
    }
  }
}

extern "C" void kernel_launch(void* const* d_in, const int* in_sizes, int n_in,
                              void* d_out, int out_size, void* d_ws, size_t ws_size,
                              hipStream_t stream) {
  const float* img  = (const float*)d_in[0];
  const int*   seg  = (const int*)  d_in[1];
  const float* c1w  = (const float*)d_in[2];
  const float* bn1g = (const float*)d_in[4];
  const float* bn1b = (const float*)d_in[5];
  const float* c2w  = (const float*)d_in[6];
  const float* bn2g = (const float*)d_in[8];
  const float* bn2b = (const float*)d_in[9];
  const float* pos  = (const float*)d_in[10];
  const float* W1   = (const float*)d_in[11];
  const float* b1   = (const float*)d_in[12];
  const float* W2   = (const float*)d_in[13];
  const float* b2   = (const float*)d_in[14];

  char* ws = (char*)d_ws;
  size_t off = 0;
  auto alloc = [&](size_t bytes) { size_t o = off; off = (off + bytes + 255) & ~(size_t)255; return o; };

  size_t oC1  = alloc((size_t)NB * NP * 64 * 2);    // conv1 out, bf16 NHWC
  size_t oY   = alloc((size_t)NB * EMB * PPR * 2);  // raw conv2 output, fp16, PADDED rows
  size_t oWr2 = alloc((size_t)9 * 768 * 64 * 2);
  size_t oWr1 = alloc(147 * 64 * 4);
  size_t oW1T = alloc((size_t)HID * EMB * 2);
  size_t oW2T = alloc((size_t)EMB * HID * 2);
  size_t oSum = alloc((NBUCK * 64 * 2 + 768 + 768) * 4);
  size_t oCoef = alloc((64 + 64 + 768 + 768) * 4);
  size_t oLast = alloc(NTOK * 4);
  size_t oX   = alloc((size_t)NTOK * EMB * 2);
  size_t oH   = alloc((size_t)NTOK * HID * 2);
  (void)ws_size; (void)in_sizes; (void)n_in;

  u16*   c1   = (u16*)(ws + oC1);
  u16*   y    = (u16*)(ws + oY);
  u16*   wr2  = (u16*)(ws + oWr2);
  float* wr1  = (float*)(ws + oWr1);
  u16*   w1t  = (u16*)(ws + oW1T);
  u16*   w2t  = (u16*)(ws + oW2T);
  float* bn1sumb = (float*)(ws + oSum);           // [NBUCK][64]
  float* bn1sqb  = bn1sumb + NBUCK * 64;          // [NBUCK][64]
  float* bn2sum  = bn1sumb + NBUCK * 64 * 2;      // [768]
  float* bn2sq   = bn2sum + 768;                  // [768]
  float* a1 = (float*)(ws + oCoef);
  float* s1 = a1 + 64;
  float* a2 = a1 + 128;
  float* s2 = a2 + 768;
  int*   lastn = (int*)(ws + oLast);
  u16*   x  = (u16*)(ws + oX);
  u16*   h  = (u16*)(ws + oH);
  float* out = (float*)d_out;

  hipMemsetAsync(ws + oSum, 0, (NBUCK * 64 * 2 + 768 + 768) * 4, stream);
  hipMemsetAsync(ws + oLast, 0xFF, NTOK * 4, stream);

  const int prep_total = PR_WR1 + PR_WR2 + PR_W1T + PR_W2T + PR_LASTN;
  k_prep<<<(prep_total + 255) / 256, 256, 0, stream>>>(c1w, c2w, W1, W2, seg,
                                                        wr1, wr2, w1t, w2t, lastn);

  k_conv1<<<dim3(7, 112, 8), 256, 0, stream>>>(img, wr1, c1, bn1sumb, bn1sqb);
  k_bncoef<<<1, 256, 0, stream>>>(bn1sumb, bn1sqb, bn1g, bn1b, a1, s1, 64, 1.f / 100352.f, NBUCK);

  k_conv2_stats<<<1600, 256, 0, stream>>>(c1, wr2, a1, s1, bn2sum, bn2sq, y);
  k_bncoef<<<3, 256, 0, stream>>>(bn2sum, bn2sq, bn2g, bn2b, a2, s2, 768, 1.f / 100352.f, 1);

  k_token_out<<<NTOK, 256, 0, stream>>>(y, lastn, a2, s2, pos, x);

  k_mlp1<<<dim3(25, 8), 256, 0, stream>>>(x, w1t, b1, h);
  k_mlp2<<<dim3(25, 12), 256, 0, stream>>>(h, w2t, b2, lastn, out);
}

// Round 19
// 257.089 us; speedup vs baseline: 1.2364x; 1.0317x over previous
//
#include <hip/hip_runtime.h>
#include <hip/hip_bf16.h>

typedef __attribute__((ext_vector_type(4))) float f32x4;
typedef __attribute__((ext_vector_type(8))) short s16x8;
typedef __attribute__((ext_vector_type(4))) short s16x4;
typedef unsigned short u16;
typedef unsigned long long u64;

#define NB 8
#define NP 12544      // 112*112 output pixels per image
#define PH 114        // padded width/height
#define PP 12996      // 114*114 padded plane
#define PPR 13056     // y row stride (padded plane rounded up, 64-elem aligned)
#define QLIM 12768    // q < QLIM && q%114 < 112  <=> valid output pixel
#define NSEG 196
#define NTOK (NB*NSEG)  // 1568
#define EMB 768
#define HID 512
#define AROWS 368     // A-tile rows staged once: 128 + max tap offset 230 + pad
#define NBUCK 32      // BN1 atomic contention-spreading buckets

__device__ __forceinline__ u16 f2b(float v) {
  __hip_bfloat16 h = __float2bfloat16(v);
  return __builtin_bit_cast(u16, h);
}
__device__ __forceinline__ float b2f(u16 u) {
  unsigned int x = ((unsigned int)u) << 16;
  return __builtin_bit_cast(float, x);
}
__device__ __forceinline__ u16 f2h(float v) {
  _Float16 h = (_Float16)v;
  return __builtin_bit_cast(u16, h);
}
__device__ __forceinline__ float h2f(u16 u) {
  _Float16 h = __builtin_bit_cast(_Float16, u);
  return (float)h;
}
__device__ __forceinline__ u64 pack4h(f32x4 v) {
  s16x4 p;
#pragma unroll
  for (int e = 0; e < 4; ++e) p[e] = (short)f2h(v[e]);
  return __builtin_bit_cast(u64, p);
}

// async global->LDS, 16B per lane; lds dest = wave-uniform base + lane*16
__device__ __forceinline__ void gl16(const u16* g, u16* l) {
  __builtin_amdgcn_global_load_lds((const __attribute__((address_space(1))) void*)g,
                                   (__attribute__((address_space(3))) void*)l, 16, 0, 0);
}

// ---------------- merged weight repacks + lastn (one launch) ----------------
#define PR_WR1 (147 * 64)
#define PR_WR2 (9 * 768 * 64)
#define PR_W1T (512 * 768)
#define PR_W2T (768 * 512)
#define PR_LASTN (NB * NP)
__global__ void k_prep(const float* __restrict__ c1w, const float* __restrict__ c2w,
                       const float* __restrict__ W1, const float* __restrict__ W2,
                       const int* __restrict__ seg,
                       float* __restrict__ wr1, u16* __restrict__ wr2,
                       u16* __restrict__ w1t, u16* __restrict__ w2t,
                       int* __restrict__ lastn) {
  int id = blockIdx.x * 256 + threadIdx.x;
  if (id < PR_WR1) {
    int co = id & 63, k = id >> 6;
    int ci = k / 49, r = k % 49, kh = r / 7, kw = r % 7;
    wr1[k * 64 + co] = c1w[((co * 3 + ci) * 7 + kh) * 7 + kw];
    return;
  }
  id -= PR_WR1;
  if (id < PR_WR2) {
    int ci = id & 63, co = (id >> 6) % 768, tap = id / (64 * 768);
    int kh = tap / 3, kw = tap % 3;
    wr2[((size_t)(tap * 768 + co)) * 64 + ci] = f2b(c2w[((co * 64 + ci) * 3 + kh) * 3 + kw]);
    return;
  }
  id -= PR_WR2;
  if (id < PR_W1T) {
    int k = id % 768, n = id / 768;
    w1t[id] = f2b(W1[(size_t)k * 512 + n]);
    return;
  }
  id -= PR_W1T;
  if (id < PR_W2T) {
    int k = id % 512, n = id / 512;
    w2t[id] = f2b(W2[(size_t)k * 768 + n]);
    return;
  }
  id -= PR_W2T;
  if (id < PR_LASTN) {
    int b = id / NP, n = id % NP;
    int oh = n / 112, ow = n % 112;
    int s = seg[((size_t)b * 224 + oh * 2) * 224 + ow * 2];
    if ((unsigned)s < 196u) atomicMax(&lastn[b * NSEG + s], n);
  }
}

// ---------------- conv1 7x7/s2/p3 -> NHWC bf16 + fused BN1 partial stats ----------------
__global__ __launch_bounds__(256) void k_conv1(const float* __restrict__ img,
                                               const float* __restrict__ wr1,
                                               u16* __restrict__ c1,
                                               float* __restrict__ sumb,
                                               float* __restrict__ sqb) {
  int owt = blockIdx.x, oh = blockIdx.y, b = blockIdx.z;
  int t = threadIdx.x;
  __shared__ float xs[3 * 7 * 37];
  __shared__ float ls[64], lq[64];
  if (t < 64) { ls[t] = 0.f; lq[t] = 0.f; }
  int iw0 = owt * 32 - 3;
  int ih0 = oh * 2 - 3;
  for (int i = t; i < 3 * 7 * 37; i += 256) {
    int ci = i / (7 * 37), r = i % (7 * 37), kh = r / 37, cc = r % 37;
    int ih = ih0 + kh, iw = iw0 + cc;
    float v = 0.f;
    if ((unsigned)ih < 224u && (unsigned)iw < 224u)
      v = img[((size_t)(b * 3 + ci) * 224 + ih) * 224 + iw];
    xs[i] = v;
  }
  __syncthreads();
  int co = t & 63, g = t >> 6;
  float a0 = 0.f, a1 = 0.f, a2 = 0.f, a3 = 0.f;
  for (int ci = 0; ci < 3; ++ci)
    for (int kh = 0; kh < 7; ++kh) {
      const float* xrow = &xs[(ci * 7 + kh) * 37];
      const float* wrow = &wr1[(ci * 49 + kh * 7) * 64 + co];
#pragma unroll
      for (int kw = 0; kw < 7; ++kw) {
        float wv = wrow[kw * 64];
        int base = g * 8 + kw;
        a0 += xrow[base + 0] * wv;
        a1 += xrow[base + 2] * wv;
        a2 += xrow[base + 4] * wv;
        a3 += xrow[base + 6] * wv;
      }
    }
  size_t p0 = (size_t)b * NP + oh * 112 + owt * 16 + g * 4;
  c1[(p0 + 0) * 64 + co] = f2b(a0);
  c1[(p0 + 1) * 64 + co] = f2b(a1);
  c1[(p0 + 2) * 64 + co] = f2b(a2);
  c1[(p0 + 3) * 64 + co] = f2b(a3);
  float s = a0 + a1 + a2 + a3;
  float q = a0 * a0 + a1 * a1 + a2 * a2 + a3 * a3;
  atomicAdd(&ls[co], s);
  atomicAdd(&lq[co], q);
  __syncthreads();
  if (t < 64) {
    int bid = owt + 7 * (oh + 112 * b);
    int bk = (bid & (NBUCK - 1)) * 64 + t;
    atomicAdd(&sumb[bk], ls[t]);
    atomicAdd(&sqb[bk], lq[t]);
  }
}

// ---------------- BN coefficients ----------------
__global__ void k_bncoef(const float* __restrict__ sumb, const float* __restrict__ sqb,
                         const float* __restrict__ g, const float* __restrict__ bb,
                         float* __restrict__ a, float* __restrict__ s, int C, float invN,
                         int nbuck) {
  int i = blockIdx.x * 256 + threadIdx.x;
  if (i >= C) return;
  float ms = 0.f, qs = 0.f;
  for (int k = 0; k < nbuck; ++k) { ms += sumb[k * C + i]; qs += sqb[k * C + i]; }
  float m = ms * invN;
  float v = qs * invN - m * m;
  float ai = g[i] * rsqrtf(v + 1e-5f);
  a[i] = ai;
  s[i] = bb[i] - m * ai;
}

// ---------------- conv2 (3x3, 64->768): A-once (BN1+ReLU fused, batched loads) + B-dbuf ----------------
// A staged ONCE from c1 via reg->ds_write with fused normalize+ReLU; loads
// batched 6-at-a-time ahead of the convert+write (hides L2 latency, r15 fix).
// Zero halo via bounds check. Swizzle on the WRITE address (c ^ (r&7)).
// B dbuf via global_load_lds (source pre-swizzled). ONE __syncthreads per tap.
// Coalesced y epilogue (r12-proven).
__global__ __launch_bounds__(256, 2) void k_conv2_stats(const u16* __restrict__ c1,
                                                        const u16* __restrict__ wr2,
                                                        const float* __restrict__ a1,
                                                        const float* __restrict__ s1,
                                                        float* __restrict__ sum,
                                                        float* __restrict__ sq,
                                                        u16* __restrict__ y) {
  const int t = threadIdx.x;
  const int lane = t & 63;
  const int w = t >> 6;
  const int wr = w >> 1, wc = w & 1;
  const int h = blockIdx.x;
  const int b = h & 7;
  const int r8 = h >> 3;            // 0..599
  const int q0 = (r8 / 6) * 128;
  const int co0 = (r8 % 6) * 128;
  const int la = lane & 15, lb = lane >> 4;

  __shared__ __align__(16) u16 As[AROWS * 64];     // 46KB; reused as 32KB y-scratch
  __shared__ __align__(16) u16 Bs[2][128 * 64];    // 2 x 16KB
  __shared__ float csum[128], csq[128];
  if (t < 128) { csum[t] = 0.f; csq[t] = 0.f; }

#define BSTAGE(tap, buf) do {                                                   \
    const u16* bsrc_ = wr2 + ((size_t)((tap) * 768 + co0)) * 64;                 \
    _Pragma("unroll")                                                            \
    for (int i_ = 0; i_ < 4; ++i_) {                                             \
      int s_ = i_ * 256 + w * 64 + lane;                                         \
      int r_ = s_ >> 3, c_ = s_ & 7;                                             \
      int cg_ = c_ ^ (r_ & 7);                                                   \
      gl16(bsrc_ + (size_t)r_ * 64 + cg_ * 8,                                    \
           &Bs[buf][(size_t)(i_ * 256 + w * 64) * 8]);                           \
    }                                                                            \
  } while (0)

  BSTAGE(0, 0);
  // stage A once from c1 with fused BN1+ReLU; loads batched ahead of converts
  {
    const u16* c1b = c1 + (size_t)b * NP * 64;
    const int c = t & 7;   // fixed channel-octet per thread
    f32x4 aLo = *(const f32x4*)&a1[c * 8];
    f32x4 aHi = *(const f32x4*)&a1[c * 8 + 4];
    f32x4 sLo = *(const f32x4*)&s1[c * 8];
    f32x4 sHi = *(const f32x4*)&s1[c * 8 + 4];
#pragma unroll
    for (int hh = 0; hh < 2; ++hh) {
      s16x8 vv[6];
      bool ok0, ok1, ok2, ok3, ok4, ok5;
#pragma unroll
      for (int i = 0; i < 6; ++i) {
        int s = (hh * 6 + i) * 256 + t;
        int r = s >> 3;
        int p = q0 + r;
        int pd = p / PH, pm = p - pd * PH;
        bool valid = (s < AROWS * 8) && (pd >= 1) && (pd <= 112) && (pm >= 1) && (pm <= 112);
        int pix = valid ? ((pd - 1) * 112 + (pm - 1)) : 0;
        vv[i] = *(const s16x8*)&c1b[(size_t)pix * 64 + c * 8];
        if (i == 0) ok0 = valid; else if (i == 1) ok1 = valid; else if (i == 2) ok2 = valid;
        else if (i == 3) ok3 = valid; else if (i == 4) ok4 = valid; else ok5 = valid;
      }
#pragma unroll
      for (int i = 0; i < 6; ++i) {
        int s = (hh * 6 + i) * 256 + t;
        if (s < AROWS * 8) {
          int r = s >> 3;
          bool valid = (i == 0) ? ok0 : (i == 1) ? ok1 : (i == 2) ? ok2
                     : (i == 3) ? ok3 : (i == 4) ? ok4 : ok5;
          s16x8 o = {0, 0, 0, 0, 0, 0, 0, 0};
          if (valid) {
            s16x8 v = vv[i];
#pragma unroll
            for (int e = 0; e < 4; ++e) {
              o[e]     = (short)f2b(fmaxf(aLo[e] * b2f((u16)v[e])     + sLo[e], 0.f));
              o[e + 4] = (short)f2b(fmaxf(aHi[e] * b2f((u16)v[e + 4]) + sHi[e], 0.f));
            }
          }
          *(s16x8*)&As[r * 64 + ((c ^ (r & 7)) * 8)] = o;
        }
      }
    }
  }
  __syncthreads();   // drains vmcnt (B0) + lgkm (A writes)

  const f32x4 zero4 = {0.f, 0.f, 0.f, 0.f};
  f32x4 acc[4][4];
#pragma unroll
  for (int i = 0; i < 4; ++i)
#pragma unroll
    for (int j = 0; j < 4; ++j) acc[i][j] = zero4;

  for (int tap = 0; tap < 9; ++tap) {
    const int off = (tap / 3) * PH + (tap % 3);
    const int buf = tap & 1;

    s16x8 af[4][2], bf[4][2];
#pragma unroll
    for (int qf = 0; qf < 4; ++qf) {
      int r = wr * 64 + qf * 16 + la + off;
      int rx = r & 7;
#pragma unroll
      for (int ks = 0; ks < 2; ++ks) {
        int slot = (ks * 4 + lb) ^ rx;
        af[qf][ks] = *(const s16x8*)&As[r * 64 + slot * 8];
      }
    }
#pragma unroll
    for (int cf = 0; cf < 4; ++cf) {
      int r = wc * 64 + cf * 16 + la;
      int rx = r & 7;
#pragma unroll
      for (int ks = 0; ks < 2; ++ks) {
        int slot = (ks * 4 + lb) ^ rx;
        bf[cf][ks] = *(const s16x8*)&Bs[buf][r * 64 + slot * 8];
      }
    }

    if (tap < 8) BSTAGE(tap + 1, buf ^ 1);   // flies under the MFMAs

#pragma unroll
    for (int ks = 0; ks < 2; ++ks)
#pragma unroll
      for (int qf = 0; qf < 4; ++qf)
#pragma unroll
        for (int cf = 0; cf < 4; ++cf)
          acc[qf][cf] = __builtin_amdgcn_mfma_f32_16x16x32_bf16(af[qf][ks], bf[cf][ks], acc[qf][cf], 0, 0, 0);

    __syncthreads();   // one barrier per tap
  }
#undef BSTAGE

  // ---- epilogue part 1: pack acc -> LDS scratch (reuse As), XOR swizzle ----
  u64* S = (u64*)As;   // [128 rows][32 chunks of 8B] = 32KB
#pragma unroll
  for (int cf = 0; cf < 4; ++cf) {
    int row = wc * 64 + cf * 16 + la;
#pragma unroll
    for (int qf = 0; qf < 4; ++qf) {
      int chunk = wr * 16 + qf * 4 + lb;
      S[row * 32 + (chunk ^ (row & 15))] = pack4h(acc[qf][cf]);
    }
  }

  // ---- stats (masked, from registers) ----
  bool vmask[16];
#pragma unroll
  for (int qf = 0; qf < 4; ++qf)
#pragma unroll
    for (int rr = 0; rr < 4; ++rr) {
      int q = q0 + wr * 64 + qf * 16 + lb * 4 + rr;
      vmask[qf * 4 + rr] = (q < QLIM) && ((q % PH) < 112);
    }
#pragma unroll
  for (int cf = 0; cf < 4; ++cf) {
    const int cob = wc * 64 + cf * 16 + la;
    float s = 0.f, ss = 0.f;
#pragma unroll
    for (int qf = 0; qf < 4; ++qf)
#pragma unroll
      for (int rr = 0; rr < 4; ++rr) {
        float v = acc[qf][cf][rr];
        if (vmask[qf * 4 + rr]) { s += v; ss += v * v; }
      }
    s += __shfl_xor(s, 16); ss += __shfl_xor(ss, 16);
    s += __shfl_xor(s, 32); ss += __shfl_xor(ss, 32);
    if (lane < 16) { atomicAdd(&csum[cob], s); atomicAdd(&csq[cob], ss); }
  }
  __syncthreads();   // S writes + csum atomics visible

  // ---- epilogue part 2: coalesced store (wave = 2 rows x 256B) ----
  {
    const size_t ybb = ((size_t)b * EMB + co0) * PPR + q0;
#pragma unroll
    for (int i = 0; i < 16; ++i) {
      int g = i * 256 + t;
      int row = g >> 5, c = g & 31;
      u64 pk = S[row * 32 + (c ^ (row & 15))];
      *(u64*)&y[ybb + (size_t)row * PPR + c * 4] = pk;
    }
  }
  if (t < 128) { atomicAdd(&sum[co0 + t], csum[t]); atomicAdd(&sq[co0 + t], csq[t]); }
}

// ---------------- token assembly: slice of padded y + BN2 + ReLU + pos -> x bf16 ----------------
__global__ __launch_bounds__(256) void k_token_out(const u16* __restrict__ y,
                                                   const int* __restrict__ lastn,
                                                   const float* __restrict__ a2,
                                                   const float* __restrict__ s2,
                                                   const float* __restrict__ pos,
                                                   u16* __restrict__ x) {
  int tok = blockIdx.x;
  int b = tok / NSEG, sg = tok % NSEG;
  int n = lastn[tok];
  int t = threadIdx.x;
  for (int c = t; c < EMB; c += 256) {
    float r = 0.f;
    if (n >= 0) {
      int j = n * EMB + c;         // flat index in unpadded [768][12544] view
      int ch = j / NP, sp = j - ch * NP;
      int qd = sp / 112, qm = sp - qd * 112;
      float v = h2f(y[((size_t)b * EMB + ch) * PPR + qd * PH + qm]);
      r = fmaxf(a2[ch] * v + s2[ch], 0.f) + pos[(size_t)sg * EMB + c];
    }
    x[(size_t)tok * EMB + c] = f2b(r);
  }
}

// ---------------- MLP layer 1: h = gelu(x @ W1 + b1) ----------------
__global__ __launch_bounds__(256) void k_mlp1(const u16* __restrict__ x,
                                              const u16* __restrict__ w1t,
                                              const float* __restrict__ b1,
                                              u16* __restrict__ h) {
  int t = threadIdx.x, lane = t & 63, w = t >> 6;
  int la = lane & 15, lb = lane >> 4;
  int m0 = (blockIdx.x * 4 + w) * 16;
  int n0 = blockIdx.y * 64;
  const f32x4 zero4 = {0.f, 0.f, 0.f, 0.f};
  f32x4 acc[4] = {zero4, zero4, zero4, zero4};
  int mrow = m0 + la; if (mrow >= NTOK) mrow = NTOK - 1;
  for (int k = 0; k < EMB; k += 32) {
    int ko = k + lb * 8;
    s16x8 a = *(const s16x8*)(x + (size_t)mrow * EMB + ko);
#pragma unroll
    for (int cf = 0; cf < 4; ++cf) {
      s16x8 bv = *(const s16x8*)(w1t + (size_t)(n0 + cf * 16 + la) * EMB + ko);
      acc[cf] = __builtin_amdgcn_mfma_f32_16x16x32_bf16(a, bv, acc[cf], 0, 0, 0);
    }
  }
#pragma unroll
  for (int cf = 0; cf < 4; ++cf) {
    int n = n0 + cf * 16 + la;
    float bias = b1[n];
#pragma unroll
    for (int r = 0; r < 4; ++r) {
      int m = m0 + lb * 4 + r;
      if (m < NTOK) {
        float v = acc[cf][r] + bias;
        float gg = 0.5f * v * (1.f + erff(v * 0.70710678118654752f));
        h[(size_t)m * HID + n] = f2b(gg);
      }
    }
  }
}

// ---------------- MLP layer 2: y = h @ W2 + b2 -> d_out (zeros for absent tokens) ----------------
__global__ __launch_bounds__(256) void k_mlp2(const u16* __restrict__ h,
                                              const u16* __restrict__ w2t,
                                              const float* __restrict__ b2,
                                              const int* __restrict__ lastn,
                                              float* __restrict__ out) {
  int t = threadIdx.x, lane = t & 63, w = t >> 6;
  int la = lane & 15, lb = lane >> 4;
  int m0 = (blockIdx.x * 4 + w) * 16;
  int n0 = blockIdx.y * 64;
  const f32x4 zero4 = {0.f, 0.f, 0.f, 0.f};
  f32x4 acc[4] = {zero4, zero4, zero4, zero4};
  int mrow = m0 + la; if (mrow >= NTOK) mrow = NTOK - 1;
  for (int k = 0; k < HID; k += 32) {
    int ko = k + lb * 8;
    s16x8 a = *(const s16x8*)(h + (size_t)mrow * HID + ko);
#pragma unroll
    for (int cf = 0; cf < 4; ++cf) {
      s16x8 bv = *(const s16x8*)(w2t + (size_t)(n0 + cf * 16 + la) * HID + ko);
      acc[cf] = __builtin_amdgcn_mfma_f32_16x16x32_bf16(a, bv, acc[cf], 0, 0, 0);
    }
  }
#pragma unroll
  for (int cf = 0; cf < 4; ++cf) {
    int n = n0 + cf * 16 + la;
    float bias = b2[n];
#pragma unroll
    for (int r = 0; r < 4; ++r) {
      int m = m0 + lb * 4 + r;
      if (m < NTOK)
        out[(size_t)m * EMB + n] = (lastn[m] >= 0) ? (acc[cf][r] + bias) : 0.f;
    }
  }
}

extern "C" void kernel_launch(void* const* d_in, const int* in_sizes, int n_in,
                              void* d_out, int out_size, void* d_ws, size_t ws_size,
                              hipStream_t stream) {
  const float* img  = (const float*)d_in[0];
  const int*   seg  = (const int*)  d_in[1];
  const float* c1w  = (const float*)d_in[2];
  const float* bn1g = (const float*)d_in[4];
  const float* bn1b = (const float*)d_in[5];
  const float* c2w  = (const float*)d_in[6];
  const float* bn2g = (const float*)d_in[8];
  const float* bn2b = (const float*)d_in[9];
  const float* pos  = (const float*)d_in[10];
  const float* W1   = (const float*)d_in[11];
  const float* b1   = (const float*)d_in[12];
  const float* W2   = (const float*)d_in[13];
  const float* b2   = (const float*)d_in[14];

  char* ws = (char*)d_ws;
  size_t off = 0;
  auto alloc = [&](size_t bytes) { size_t o = off; off = (off + bytes + 255) & ~(size_t)255; return o; };

  size_t oC1  = alloc((size_t)NB * NP * 64 * 2);    // conv1 out, bf16 NHWC
  size_t oY   = alloc((size_t)NB * EMB * PPR * 2);  // raw conv2 output, fp16, PADDED rows
  size_t oWr2 = alloc((size_t)9 * 768 * 64 * 2);
  size_t oWr1 = alloc(147 * 64 * 4);
  size_t oW1T = alloc((size_t)HID * EMB * 2);
  size_t oW2T = alloc((size_t)EMB * HID * 2);
  size_t oSum = alloc((NBUCK * 64 * 2 + 768 + 768) * 4);
  size_t oCoef = alloc((64 + 64 + 768 + 768) * 4);
  size_t oLast = alloc(NTOK * 4);
  size_t oX   = alloc((size_t)NTOK * EMB * 2);
  size_t oH   = alloc((size_t)NTOK * HID * 2);
  (void)ws_size; (void)in_sizes; (void)n_in;

  u16*   c1   = (u16*)(ws + oC1);
  u16*   y    = (u16*)(ws + oY);
  u16*   wr2  = (u16*)(ws + oWr2);
  float* wr1  = (float*)(ws + oWr1);
  u16*   w1t  = (u16*)(ws + oW1T);
  u16*   w2t  = (u16*)(ws + oW2T);
  float* bn1sumb = (float*)(ws + oSum);           // [NBUCK][64]
  float* bn1sqb  = bn1sumb + NBUCK * 64;          // [NBUCK][64]
  float* bn2sum  = bn1sumb + NBUCK * 64 * 2;      // [768]
  float* bn2sq   = bn2sum + 768;                  // [768]
  float* a1 = (float*)(ws + oCoef);
  float* s1 = a1 + 64;
  float* a2 = a1 + 128;
  float* s2 = a2 + 768;
  int*   lastn = (int*)(ws + oLast);
  u16*   x  = (u16*)(ws + oX);
  u16*   h  = (u16*)(ws + oH);
  float* out = (float*)d_out;

  hipMemsetAsync(ws + oSum, 0, (NBUCK * 64 * 2 + 768 + 768) * 4, stream);
  hipMemsetAsync(ws + oLast, 0xFF, NTOK * 4, stream);

  const int prep_total = PR_WR1 + PR_WR2 + PR_W1T + PR_W2T + PR_LASTN;
  k_prep<<<(prep_total + 255) / 256, 256, 0, stream>>>(c1w, c2w, W1, W2, seg,
                                                        wr1, wr2, w1t, w2t, lastn);

  k_conv1<<<dim3(7, 112, 8), 256, 0, stream>>>(img, wr1, c1, bn1sumb, bn1sqb);
  k_bncoef<<<1, 256, 0, stream>>>(bn1sumb, bn1sqb, bn1g, bn1b, a1, s1, 64, 1.f / 100352.f, NBUCK);

  k_conv2_stats<<<4800, 256, 0, stream>>>(c1, wr2, a1, s1, bn2sum, bn2sq, y);
  k_bncoef<<<3, 256, 0, stream>>>(bn2sum, bn2sq, bn2g, bn2b, a2, s2, 768, 1.f / 100352.f, 1);

  k_token_out<<<NTOK, 256, 0, stream>>>(y, lastn, a2, s2, pos, x);

  k_mlp1<<<dim3(25, 8), 256, 0, stream>>>(x, w1t, b1, h);
  k_mlp2<<<dim3(25, 12), 256, 0, stream>>>(h, w2t, b2, lastn, out);
}